// Round 6
// baseline (295.307 us; speedup 1.0000x reference)
//
#include <hip/hip_runtime.h>
#include <hip/hip_fp16.h>

typedef _Float16 f16;
typedef _Float16 f16x2 __attribute__((ext_vector_type(2)));
typedef _Float16 f16x8 __attribute__((ext_vector_type(8)));

// workspace layout (needs 1.5 MB; prior rounds used 2 MB successfully)
#define WS_XS 0              // f32[512]  sorted x values (ascending)
#define WS_JO 2048           // i32[512]  original j index per sorted position
#define WS_W2H 4096          // f16[1024*128] W2 cast to f16 (256 KB)
#define WS_K (1 << 19)       // f32[512*512] full K matrix (1 MB)

// ---------------------------------------------------------------------------
// k_prep: (a) bitonic-sort x (512 values) -> xsorted + jorig; (b) W2 -> f16.
// One block, 512 threads, ~2-3 us.
// ---------------------------------------------------------------------------
__global__ __launch_bounds__(512) void k_prep(const float* __restrict__ x,
                                              const float* __restrict__ W2,
                                              char* __restrict__ ws) {
  __shared__ float xv[512];
  __shared__ int xj[512];
  const int tid = threadIdx.x;
  xv[tid] = x[tid];
  xj[tid] = tid;
  __syncthreads();
  for (int k2 = 2; k2 <= 512; k2 <<= 1) {
    for (int j2 = k2 >> 1; j2 >= 1; j2 >>= 1) {
      const int partner = tid ^ j2;
      if (partner > tid) {
        const bool asc = ((tid & k2) == 0);
        const float a = xv[tid], b = xv[partner];
        const bool sw = asc ? (a > b) : (a < b);
        if (sw) {
          xv[tid] = b; xv[partner] = a;
          const int ja = xj[tid]; xj[tid] = xj[partner]; xj[partner] = ja;
        }
      }
      __syncthreads();
    }
  }
  ((float*)(ws + WS_XS))[tid] = xv[tid];
  ((int*)(ws + WS_JO))[tid] = xj[tid];

  f16* __restrict__ w2h = (f16*)(ws + WS_W2H);
  for (int base = tid * 8; base < 1024 * 128; base += 512 * 8) {
    const float4 a = *(const float4*)(W2 + base);
    const float4 b = *(const float4*)(W2 + base + 4);
    f16x8 o;
    o[0] = (f16)a.x; o[1] = (f16)a.y; o[2] = (f16)a.z; o[3] = (f16)a.w;
    o[4] = (f16)b.x; o[5] = (f16)b.y; o[6] = (f16)b.z; o[7] = (f16)b.w;
    *(f16x8*)(w2h + base) = o;
  }
}

// ---------------------------------------------------------------------------
// k_sweep (R26): piecewise-linear sweep. One block per i (512 blocks, 256 thr
// = 4 waves, 2 blocks/CU).
// For fixed i: S_n(x_j) = A_n x_j + B_n between breakpoints bp_k = -t_k/c_k,
// t_k = a_k x_i + b_k. Events (count-sorted by sorted-x position):
//   c>0: k activates at pos = lower_bound(xs, bp)  (delta +c,+t)
//   c<0: k active from start (event at pos 0, +) and deactivates at pos (-)
//   c==0 && t>0: always active (event at pos 0)
// Boundary ties are benign: contribution at the boundary is exactly 0.
// Wave w owns position quarter [128w, 128(w+1)); lane owns n = 2*lane,
// 2*lane+1 (A,B in 4 regs). Cross-wave checkpoint: wave w bulk-sums its own
// quarter's deltas, prefix-exchanged via LDS -> initial (A,B) per wave.
// Event application: batched 8 with prefetched LDS event data + coalesced
// f16x2 W2 loads (L2-resident); per-event emit-boundary check is register-
// cached (nextB) so the common case does zero LDS reads. Emission: per-lane
// 2-n relu-dot, 6x shfl_xor reduce, lane0 -> LDS outls; final coalesced-ish
// flush K[i*512 + jorig[p]] = outls[p] + b3.
// Replaces 34 GFLOP of MFMA with ~0.5 GFLOP + ~400 MB L2 W2 gather.
// ---------------------------------------------------------------------------
__global__ __launch_bounds__(256, 2) void k_sweep(
    const float* __restrict__ x, const float* __restrict__ W1,
    const float* __restrict__ b1, const float* __restrict__ b2,
    const float* __restrict__ W3, const float* __restrict__ b3,
    const char* __restrict__ ws, float* __restrict__ Kf) {
  __shared__ float xsp[512];
  __shared__ int jof[512];
  __shared__ float evc[2048], evt[2048];
  __shared__ unsigned short evk[2048];
  __shared__ int startS[513];
  __shared__ int histS[513];          // histogram, then scatter cursor
  __shared__ float chkA[4][128], chkB[4][128];
  __shared__ float outls[512];

  const int tid = threadIdx.x;
  const int lane = tid & 63, wv = tid >> 6;
  const int i = (int)blockIdx.x;
  const float xi = x[i];
  const f16* __restrict__ w2h = (const f16*)(ws + WS_W2H);

  {  // stage sorted x / jorig; zero histogram
    const float* xsg = (const float*)(ws + WS_XS);
    const int* jog = (const int*)(ws + WS_JO);
    xsp[tid] = xsg[tid];       xsp[tid + 256] = xsg[tid + 256];
    jof[tid] = jog[tid];       jof[tid + 256] = jog[tid + 256];
    histS[tid] = 0;            histS[tid + 256] = 0;
    if (tid == 0) histS[512] = 0;
  }
  __syncthreads();

  // --- P1: per-k event classification + histogram (4 k per thread)
  float kc[4], kt[4];
  int kpos[4];
#pragma unroll
  for (int r = 0; r < 4; r++) {
    const int k = tid + 256 * r;
    const float a = W1[k], c = W1[1024 + k], b = b1[k];
    const float t = fmaf(a, xi, b);
    kc[r] = c; kt[r] = t;
    int pos = 0;
    if (c != 0.f) {
      const float bp = -t / c;
#pragma unroll
      for (int s = 256; s > 0; s >>= 1)
        if (pos + s <= 512 && xsp[pos + s - 1] < bp) pos += s;
    }
    kpos[r] = pos;
    if (c > 0.f) {
      atomicAdd(&histS[pos], 1);
    } else if (c < 0.f) {
      atomicAdd(&histS[0], 1);
      atomicAdd(&histS[pos], 1);
    } else if (t > 0.f) {
      atomicAdd(&histS[0], 1);
    }
  }
  __syncthreads();

  // --- scan: startS[p] = sum_{q<p} histS[q] for p in [0,512] (wave 0)
  if (wv == 0) {
    int hloc[8], s8 = 0;
#pragma unroll
    for (int u = 0; u < 8; u++) { hloc[u] = histS[lane * 8 + u]; s8 += hloc[u]; }
    int incl = s8;
#pragma unroll
    for (int d = 1; d < 64; d <<= 1) {
      const int o = __shfl_up(incl, d, 64);
      if (lane >= d) incl += o;
    }
    int run = incl - s8;
#pragma unroll
    for (int u = 0; u < 8; u++) { startS[lane * 8 + u] = run; run += hloc[u]; }
    if (lane == 63) startS[512] = incl;
  }
  __syncthreads();
  // cursor = copy of start (pos-512 events land in slack past startS[512])
  histS[tid] = startS[tid];
  histS[tid + 256] = startS[tid + 256];
  if (tid == 0) histS[512] = startS[512];
  __syncthreads();

  // --- scatter events in position order
#pragma unroll
  for (int r = 0; r < 4; r++) {
    const int k = tid + 256 * r;
    const float c = kc[r], t = kt[r];
    if (c > 0.f) {
      const int sl = atomicAdd(&histS[kpos[r]], 1);
      evc[sl] = c; evt[sl] = t; evk[sl] = (unsigned short)k;
    } else if (c < 0.f) {
      int sl = atomicAdd(&histS[0], 1);
      evc[sl] = c; evt[sl] = t; evk[sl] = (unsigned short)k;
      sl = atomicAdd(&histS[kpos[r]], 1);
      evc[sl] = -c; evt[sl] = -t; evk[sl] = (unsigned short)k;
    } else if (t > 0.f) {
      const int sl = atomicAdd(&histS[0], 1);
      evc[sl] = 0.f; evt[sl] = t; evk[sl] = (unsigned short)k;
    }
  }
  __syncthreads();

  // --- P2: sweep. lane owns n0 = 2*lane, n1 = 2*lane+1.
  const int n0 = 2 * lane;
  const float b2n0 = b2[n0], b2n1 = b2[n0 + 1];
  const float w3n0 = W3[n0], w3n1 = W3[n0 + 1];

  const int csBeg = startS[wv * 128];
  const int csEnd = startS[(wv + 1) * 128];

  // checkpoint: bulk-sum own quarter's deltas, prefix-exchange across waves
  {
    float dA0 = 0.f, dB0 = 0.f, dA1 = 0.f, dB1 = 0.f;
    for (int e = csBeg; e < csEnd; e += 8) {
      float pc[8], pt[8], pw0[8], pw1[8];
#pragma unroll
      for (int u = 0; u < 8; u++) {
        const int idx = min(e + u, 2047);
        pc[u] = evc[idx]; pt[u] = evt[idx];
        const int k = evk[idx] & 1023;
        const f16x2 wp = *(const f16x2*)(w2h + k * 128 + n0);
        pw0[u] = (float)wp[0]; pw1[u] = (float)wp[1];
      }
#pragma unroll
      for (int u = 0; u < 8; u++) {
        if (e + u < csEnd) {
          dA0 = fmaf(pc[u], pw0[u], dA0); dB0 = fmaf(pt[u], pw0[u], dB0);
          dA1 = fmaf(pc[u], pw1[u], dA1); dB1 = fmaf(pt[u], pw1[u], dB1);
        }
      }
    }
    chkA[wv][n0] = dA0; chkA[wv][n0 + 1] = dA1;
    chkB[wv][n0] = dB0; chkB[wv][n0 + 1] = dB1;
  }
  __syncthreads();

  float A0 = 0.f, B0 = 0.f, A1 = 0.f, B1 = 0.f;
  for (int u = 0; u < wv; u++) {
    A0 += chkA[u][n0]; A1 += chkA[u][n0 + 1];
    B0 += chkB[u][n0]; B1 += chkB[u][n0 + 1];
  }

  // interleaved event-apply + emission over this wave's 128 positions
  {
    int p = wv * 128;
    const int p1 = p + 128;
    int e = csBeg;
    const int eEnd = csEnd;
    int nextB = startS[p + 1];

    auto EMIT = [&](int pp) {
      const float xp = xsp[pp];
      float v = fmaxf(fmaf(A0, xp, B0) + b2n0, 0.f) * w3n0 +
                fmaxf(fmaf(A1, xp, B1) + b2n1, 0.f) * w3n1;
#pragma unroll
      for (int d = 1; d < 64; d <<= 1) v += __shfl_xor(v, d, 64);
      if (lane == 0) outls[pp] = v;
    };

    while (p < p1) {
      while (p < p1 && nextB <= e) {
        EMIT(p); p++;
        if (p < p1) nextB = startS[p + 1];
      }
      if (p >= p1) break;
      float pc[8], pt[8], pw0[8], pw1[8];
#pragma unroll
      for (int u = 0; u < 8; u++) {
        const int idx = min(e + u, 2047);
        pc[u] = evc[idx]; pt[u] = evt[idx];
        const int k = evk[idx] & 1023;
        const f16x2 wp = *(const f16x2*)(w2h + k * 128 + n0);
        pw0[u] = (float)wp[0]; pw1[u] = (float)wp[1];
      }
#pragma unroll
      for (int u = 0; u < 8; u++) {
        if (e + u >= nextB) {  // emit positions whose events are now complete
          while (p < p1 && nextB <= e + u) {
            EMIT(p); p++;
            if (p < p1) nextB = startS[p + 1];
          }
        }
        if (e + u < eEnd) {
          A0 = fmaf(pc[u], pw0[u], A0); B0 = fmaf(pt[u], pw0[u], B0);
          A1 = fmaf(pc[u], pw1[u], A1); B1 = fmaf(pt[u], pw1[u], B1);
        }
      }
      e += 8;
    }
  }
  __syncthreads();

  // --- flush: K[i, jorig[p]] = outls[p] + b3 (full row overwrite)
  const float b3v = b3[0];
#pragma unroll
  for (int r = 0; r < 2; r++) {
    const int pp = tid + 256 * r;
    Kf[i * 512 + jof[pp]] = outls[pp] + b3v;
  }
}

// ---------------------------------------------------------------------------
// k_ktk (R21 tile-ownership KtK, adapted to single K input). 136 blocks
// (chunk-pair a<=b); block owns C[pb:pb+32, qb:qb+32] + mirror; reduction
// depth = a+1 chunks (triangular K: row r contributes iff r <= col). Direct
// stores fully overwrite C -> no pre-zero anywhere.
// ---------------------------------------------------------------------------
__global__ __launch_bounds__(256) void k_ktk(const float* __restrict__ K0,
                                             float* __restrict__ C) {
  __shared__ __align__(16) float sp[2][32 * 36];
  __shared__ __align__(16) float sq[2][32 * 36];

  int a = 0, rem = (int)blockIdx.x;
#pragma unroll
  for (int aa = 0; aa < 16; aa++) {
    const int c = 16 - aa;
    if (rem < c) { a = aa; break; }
    rem -= c;
  }
  const int b = a + rem;
  const int pb = a * 32, qb = b * 32;
  const int nchunk = a + 1;

  const int tid = threadIdx.x;
  const int ii = tid >> 3, p4 = (tid & 7) << 2;
  const int tx = tid & 15, ty = tid >> 4;

  float4 x0, y0;
  {
    const int gp = ii * 512 + pb + p4, gq = ii * 512 + qb + p4;
    x0 = *(const float4*)(K0 + gp);
    y0 = *(const float4*)(K0 + gq);
  }

  float c00 = 0.f, c01 = 0.f, c10 = 0.f, c11 = 0.f;

  for (int ic = 0; ic < nchunk; ic++) {
    float* __restrict__ spb = sp[ic & 1];
    float* __restrict__ sqb = sq[ic & 1];
    const int r = ic * 32 + ii;
    float4 vp, vq;
    vp.x = (r <= pb + p4 + 0) ? x0.x : 0.f;
    vp.y = (r <= pb + p4 + 1) ? x0.y : 0.f;
    vp.z = (r <= pb + p4 + 2) ? x0.z : 0.f;
    vp.w = (r <= pb + p4 + 3) ? x0.w : 0.f;
    vq.x = (r <= qb + p4 + 0) ? y0.x : 0.f;
    vq.y = (r <= qb + p4 + 1) ? y0.y : 0.f;
    vq.z = (r <= qb + p4 + 2) ? y0.z : 0.f;
    vq.w = (r <= qb + p4 + 3) ? y0.w : 0.f;
    *(float4*)&spb[ii * 36 + p4] = vp;
    *(float4*)&sqb[ii * 36 + p4] = vq;
    __syncthreads();

    if (ic + 1 < nchunk) {
      const int r2 = (ic + 1) * 32 + ii;
      const int gp = r2 * 512 + pb + p4, gq = r2 * 512 + qb + p4;
      x0 = *(const float4*)(K0 + gp);
      y0 = *(const float4*)(K0 + gq);
    }

#pragma unroll 8
    for (int k = 0; k < 32; k++) {
      const float2 av = *(const float2*)&spb[k * 36 + ty * 2];
      const float2 bv = *(const float2*)&sqb[k * 36 + tx * 2];
      c00 = fmaf(av.x, bv.x, c00); c01 = fmaf(av.x, bv.y, c01);
      c10 = fmaf(av.y, bv.x, c10); c11 = fmaf(av.y, bv.y, c11);
    }
  }

  const int p0 = pb + ty * 2, q0 = qb + tx * 2;
  *(float2*)&C[p0 * 512 + q0]       = make_float2(c00, c01);
  *(float2*)&C[(p0 + 1) * 512 + q0] = make_float2(c10, c11);
  if (pb != qb) {
    *(float2*)&C[q0 * 512 + p0]       = make_float2(c00, c10);
    *(float2*)&C[(q0 + 1) * 512 + p0] = make_float2(c01, c11);
  }
}

extern "C" void kernel_launch(void* const* d_in, const int* in_sizes, int n_in,
                              void* d_out, int out_size, void* d_ws, size_t ws_size,
                              hipStream_t stream) {
  const float* x  = (const float*)d_in[0];
  const float* W1 = (const float*)d_in[1];
  const float* b1 = (const float*)d_in[2];
  const float* W2 = (const float*)d_in[3];
  const float* b2 = (const float*)d_in[4];
  const float* W3 = (const float*)d_in[5];
  const float* b3 = (const float*)d_in[6];
  float* out = (float*)d_out;
  char* ws = (char*)d_ws;
  float* Kf = (float*)(ws + WS_K);

  k_prep<<<1, 512, 0, stream>>>(x, W2, ws);
  k_sweep<<<512, 256, 0, stream>>>(x, W1, b1, b2, W3, b3, ws, Kf);
  k_ktk<<<136, 256, 0, stream>>>(Kf, out);
}

// Round 7
// 118.441 us; speedup vs baseline: 2.4933x; 2.4933x over previous
//
#include <hip/hip_runtime.h>
#include <hip/hip_fp16.h>

typedef _Float16 f16;
typedef _Float16 f16x8 __attribute__((ext_vector_type(8)));
typedef float f32x4 __attribute__((ext_vector_type(4)));

__device__ __forceinline__ f16x8 relu8(f16x8 a) {
#if __has_builtin(__builtin_elementwise_max)
  return __builtin_elementwise_max(a, (f16x8)(f16)0);   // v_pk_max_f16 x4
#else
  f16x8 r;
#pragma unroll
  for (int i = 0; i < 8; i++) r[i] = a[i] > (f16)0 ? a[i] : (f16)0;
  return r;
#endif
}

__device__ __forceinline__ f16x8 bcast8(f16 s) {
  return (f16x8){s, s, s, s, s, s, s, s};
}

// ---------------------------------------------------------------------------
// fused (R27 = R24 revert, session best: total 119.2-119.4 us, k_fused 46.4).
// 256 persistent blocks, 512 thr = 8 waves, 1 block/CU.
// - 16x16x32 MFMA, wave tile rg=8 x cg=4 (acc 128 AGPR).
// - Branch-free hot path for the 192 full tasks (rgmin==0 always there);
//   guarded copy only for cheap diagonal tasks.
// - s_setprio(1) around each 4-MFMA cluster.
// REGISTER WALL (measured, R22-R26): acc 128 AGPR + ~124 VGPR = 252/256 at
// 2 waves/SIMD. All escape routes refuted on hardware:
//   R22 halve-acc+dbuf: doubles LDS reads/MFMA -> per-CU LDS pipe ceiling.
//   R23 4 waves/SIMD: acc spills (WRITE_SIZE 23 MB, FETCH 11 GB canaries).
//   R25 wave-staggered kk: runtime bounds kill compiler pipelining (-9%).
//   R26 piecewise-linear sweep: latency-chained serial structure, 206 us
//     (VALUBusy 29% = 60 us issue + 146 us stall; 974K LDS conflicts).
// Budget: ~66 us harness-fixed + ~47 k_fused + ~6 k_atta2.
// Canaries: VGPR 124, WRITE_SIZE ~1.0 MB, FETCH ~1.2 MB, absmax 4.0.
// ---------------------------------------------------------------------------
__global__ __launch_bounds__(512, 2) void k_fused(
    const float* __restrict__ x, const float* __restrict__ W1,
    const float* __restrict__ b1, const float* __restrict__ b2,
    const float* __restrict__ W3, const float* __restrict__ b3,
    const float* __restrict__ W2,
    float* __restrict__ Kp0, float* __restrict__ Kp1) {
  __shared__ f16 w2f[65536];                 // 128 KB: current nh's B-fragments
  __shared__ f16 w1af[1024], b1f[1024], w1bf[1024];
  __shared__ f16 hat[8192];                  // 16 KB: ha rows for task's 8 i
  __shared__ f16 xs[512];                    // f16(x)

  const int tid = threadIdx.x;
  const int lane = tid & 63, wv = tid >> 6;
  const int cL = lane & 15, q = lane >> 4;

  // --- one-time staging: W1 tables + f16(x)
  if (tid < 128) {
    const int c8 = tid << 3;
    const float4 a0 = *(const float4*)(W1 + c8);
    const float4 a1 = *(const float4*)(W1 + c8 + 4);
    const float4 g0 = *(const float4*)(b1 + c8);
    const float4 g1 = *(const float4*)(b1 + c8 + 4);
    f16x8 oa, og;
    oa[0] = (f16)a0.x; oa[1] = (f16)a0.y; oa[2] = (f16)a0.z; oa[3] = (f16)a0.w;
    oa[4] = (f16)a1.x; oa[5] = (f16)a1.y; oa[6] = (f16)a1.z; oa[7] = (f16)a1.w;
    og[0] = (f16)g0.x; og[1] = (f16)g0.y; og[2] = (f16)g0.z; og[3] = (f16)g0.w;
    og[4] = (f16)g1.x; og[5] = (f16)g1.y; og[6] = (f16)g1.z; og[7] = (f16)g1.w;
    *(f16x8*)(&w1af[c8]) = oa;
    *(f16x8*)(&b1f[c8]) = og;
  } else if (tid < 256) {
    const int c8 = (tid - 128) << 3;
    const float4 a0 = *(const float4*)(W1 + 1024 + c8);
    const float4 a1 = *(const float4*)(W1 + 1024 + c8 + 4);
    f16x8 ob;
    ob[0] = (f16)a0.x; ob[1] = (f16)a0.y; ob[2] = (f16)a0.z; ob[3] = (f16)a0.w;
    ob[4] = (f16)a1.x; ob[5] = (f16)a1.y; ob[6] = (f16)a1.z; ob[7] = (f16)a1.w;
    *(f16x8*)(&w1bf[c8]) = ob;
  } else if (tid < 320) {
    const int c8 = (tid - 256) << 3;
    const float4 x0 = *(const float4*)(x + c8);
    const float4 x1 = *(const float4*)(x + c8 + 4);
    f16x8 ox;
    ox[0] = (f16)x0.x; ox[1] = (f16)x0.y; ox[2] = (f16)x0.z; ox[3] = (f16)x0.w;
    ox[4] = (f16)x1.x; ox[5] = (f16)x1.y; ox[6] = (f16)x1.z; ox[7] = (f16)x1.w;
    *(f16x8*)(&xs[c8]) = ox;
  }

  int cur_nh = -1;

  for (int t = (int)blockIdx.x; t < 320; t += 256) {
    // --- task map (R14): cheap diagonal in {0..63, 256..319}, full in {64..255}
    int nh, jt, s;
    if (t < 64 || t >= 256) {
      const int b = (t < 64) ? t : (t - 256);
      nh = b & 1;
      const int jd = b >> 1;              // 0..31
      const int jt1 = jd >> 4, l = jd & 15;
      if (t < 64) { jt = jt1;            s = jt * 16 + l; }
      else        { jt = (jt1 + 2) & 3;  s = jt * 16 + (15 - l); }
    } else {
      const int f = t - 64;               // 0..191
      nh = f & 1;
      const int jf = f >> 1;              // 0..95
      if (jf < 16)      { jt = 1; s = jf; }
      else if (jf < 48) { jt = 2; s = jf - 16; }
      else              { jt = 3; s = jf - 48; }
    }
    const int i0 = s << 3, j0 = jt << 7;
    float* __restrict__ Kp = nh ? Kp1 : Kp0;

    __syncthreads();                  // prior task's LDS reads done; covers one-time staging
    if (nh != cur_nh) {               // gather this nh's W2 fragments from GLOBAL
      #pragma unroll
      for (int p = 0; p < 16; p++) {
        const int sl = p * 512 + tid;           // slot 0..8191
        const int frag = sl >> 6, l = sl & 63;
        const int cgL = frag >> 5, kb2 = frag & 31;
        const int q2 = l >> 4, cL2 = l & 15;
        const int n = nh * 64 + cgL * 16 + cL2;
        const float* src = W2 + (kb2 * 32 + q2 * 8) * 128 + n;
        f16x8 o;
        #pragma unroll
        for (int e = 0; e < 8; e++) o[e] = (f16)src[e * 128];
        *(f16x8*)(&w2f[frag * 512 + l * 8]) = o;
      }
      cur_nh = nh;
    }
    {  // hat[il][k] = f16(x[i0+il]*W1a[k] + b1[k]); 512 thr x 16 f16
      const int il_s = tid >> 6, kb = (tid & 63) << 4;
      const f16x8 xv = bcast8(xs[i0 + il_s]);
      const f16x8 wa0 = *(const f16x8*)(&w1af[kb]);
      const f16x8 wa1 = *(const f16x8*)(&w1af[kb + 8]);
      const f16x8 bb0 = *(const f16x8*)(&b1f[kb]);
      const f16x8 bb1 = *(const f16x8*)(&b1f[kb + 8]);
      *(f16x8*)(&hat[il_s * 1024 + kb])     = xv * wa0 + bb0;
      *(f16x8*)(&hat[il_s * 1024 + kb + 8]) = xv * wa1 + bb1;
    }
    __syncthreads();

    const int i = i0 + wv;
    const int dij = i - j0;
    const int rgmin = (dij > 0) ? (dij >> 4) : 0;   // wave-uniform skip

    f16 xjs[8];
    #pragma unroll
    for (int rg = 0; rg < 8; rg++) xjs[rg] = xs[j0 + rg * 16 + cL];

    f32x4 acc[8][4];
    #pragma unroll
    for (int rg = 0; rg < 8; rg++)
      #pragma unroll
      for (int cg = 0; cg < 4; cg++) acc[rg][cg] = (f32x4){0.f, 0.f, 0.f, 0.f};

    const f16* hrow  = hat + wv * 1024 + q * 8;
    const f16* wrow  = w1bf + q * 8;
    const f16* bbase = w2f + lane * 8;

    if (rgmin == 0) {
      // HOT PATH: all 192 full tasks + diagonal waves with i <= j0.
      // Single basic block per kk -> free cross-rg interleave.
      for (int kk = 0; kk < 32; ++kk) {
        const f16x8 hv = *(const f16x8*)(hrow + kk * 32);
        const f16x8 wb = *(const f16x8*)(wrow + kk * 32);
        f16x8 bf[4];
        #pragma unroll
        for (int cg = 0; cg < 4; cg++)
          bf[cg] = *(const f16x8*)(bbase + (cg * 32 + kk) * 512);
        #pragma unroll
        for (int rg = 0; rg < 8; rg++) {
          const f16x8 af = relu8(bcast8(xjs[rg]) * wb + hv);
          __builtin_amdgcn_s_setprio(1);
          #pragma unroll
          for (int cg = 0; cg < 4; cg++)
            acc[rg][cg] = __builtin_amdgcn_mfma_f32_16x16x32_f16(af, bf[cg], acc[rg][cg], 0, 0, 0);
          __builtin_amdgcn_s_setprio(0);
        }
      }
    } else {
      for (int kk = 0; kk < 32; ++kk) {
        const f16x8 hv = *(const f16x8*)(hrow + kk * 32);
        const f16x8 wb = *(const f16x8*)(wrow + kk * 32);
        f16x8 bf[4];
        #pragma unroll
        for (int cg = 0; cg < 4; cg++)
          bf[cg] = *(const f16x8*)(bbase + (cg * 32 + kk) * 512);
        #pragma unroll
        for (int rg = 0; rg < 8; rg++) {
          if (rg >= rgmin) {
            const f16x8 af = relu8(bcast8(xjs[rg]) * wb + hv);
            __builtin_amdgcn_s_setprio(1);
            #pragma unroll
            for (int cg = 0; cg < 4; cg++)
              acc[rg][cg] = __builtin_amdgcn_mfma_f32_16x16x32_f16(af, bf[cg], acc[rg][cg], 0, 0, 0);
            __builtin_amdgcn_s_setprio(0);
          }
        }
      }
    }

    // --- epilogue: dot over this nh's 64 n; direct global writes (1 i/wave)
    float b2v[4], w3v[4];
    #pragma unroll
    for (int cg = 0; cg < 4; cg++) {
      b2v[cg] = b2[nh * 64 + cg * 16 + cL];
      w3v[cg] = W3[nh * 64 + cg * 16 + cL];
    }
    const float badd = (nh == 0) ? b3[0] : 0.f;   // b3 added exactly once
    #pragma unroll
    for (int rg = 0; rg < 8; rg++) {
      if (rg >= rgmin) {
        #pragma unroll
        for (int r = 0; r < 4; r++) {
          float ssum = 0.f;
          #pragma unroll
          for (int cg = 0; cg < 4; cg++)
            ssum = fmaf(fmaxf(acc[rg][cg][r] + b2v[cg], 0.f), w3v[cg], ssum);
          ssum += __shfl_xor(ssum, 1, 64);
          ssum += __shfl_xor(ssum, 2, 64);
          ssum += __shfl_xor(ssum, 4, 64);
          ssum += __shfl_xor(ssum, 8, 64);
          if (cL == 0) {
            const int j = j0 + rg * 16 + q * 4 + r;  // C row = q*4 + reg
            if (j >= i) Kp[i * 512 + j] = ssum + badd;
          }
        }
      }
    }
  }
}

// ---------------------------------------------------------------------------
// atta2 (R21, proven): tile-ownership KtK, no atomics. 136 blocks (chunk-pair
// a<=b); block owns C[pb:pb+32, qb:qb+32] + mirror; reduction depth = a+1
// chunks (triangular K). Ping-pong LDS, prefetch under FMA loop, triu mask at
// LDS-store. Direct stores fully overwrite C -> no pre-zero anywhere.
// ~6 us (never in top-5).
// ---------------------------------------------------------------------------
__global__ __launch_bounds__(256) void k_atta2(const float* __restrict__ K0,
                                               const float* __restrict__ K1,
                                               float* __restrict__ C) {
  __shared__ __align__(16) float sp[2][32 * 36];
  __shared__ __align__(16) float sq[2][32 * 36];

  int a = 0, rem = (int)blockIdx.x;
  #pragma unroll
  for (int aa = 0; aa < 16; aa++) {
    const int c = 16 - aa;
    if (rem < c) { a = aa; break; }
    rem -= c;
  }
  const int b = a + rem;
  const int pb = a * 32, qb = b * 32;
  const int nchunk = a + 1;               // K[i,p]=0 for i>p  =>  i < (a+1)*32

  const int tid = threadIdx.x;
  const int ii = tid >> 3, p4 = (tid & 7) << 2;   // loader: 32 rows x 8 quads
  const int tx = tid & 15, ty = tid >> 4;         // compute: 16x16, 2x2 micro

  // prefetch chunk 0
  float4 x0, x1, y0, y1;
  {
    const int gp = ii * 512 + pb + p4, gq = ii * 512 + qb + p4;
    x0 = *(const float4*)(K0 + gp);
    x1 = *(const float4*)(K1 + gp);
    y0 = *(const float4*)(K0 + gq);
    y1 = *(const float4*)(K1 + gq);
  }

  float c00 = 0.f, c01 = 0.f, c10 = 0.f, c11 = 0.f;

  for (int ic = 0; ic < nchunk; ic++) {
    float* __restrict__ spb = sp[ic & 1];
    float* __restrict__ sqb = sq[ic & 1];
    const int r = ic * 32 + ii;
    // triu mask (lower triangle of Kp0/Kp1 is garbage workspace)
    float4 vp, vq;
    vp.x = (r <= pb + p4 + 0) ? x0.x + x1.x : 0.f;
    vp.y = (r <= pb + p4 + 1) ? x0.y + x1.y : 0.f;
    vp.z = (r <= pb + p4 + 2) ? x0.z + x1.z : 0.f;
    vp.w = (r <= pb + p4 + 3) ? x0.w + x1.w : 0.f;
    vq.x = (r <= qb + p4 + 0) ? y0.x + y1.x : 0.f;
    vq.y = (r <= qb + p4 + 1) ? y0.y + y1.y : 0.f;
    vq.z = (r <= qb + p4 + 2) ? y0.z + y1.z : 0.f;
    vq.w = (r <= qb + p4 + 3) ? y0.w + y1.w : 0.f;
    *(float4*)&spb[ii * 36 + p4] = vp;
    *(float4*)&sqb[ii * 36 + p4] = vq;
    __syncthreads();

    if (ic + 1 < nchunk) {   // issue next chunk's loads under the FMA loop
      const int r2 = (ic + 1) * 32 + ii;
      const int gp = r2 * 512 + pb + p4, gq = r2 * 512 + qb + p4;
      x0 = *(const float4*)(K0 + gp);
      x1 = *(const float4*)(K1 + gp);
      y0 = *(const float4*)(K0 + gq);
      y1 = *(const float4*)(K1 + gq);
    }

    #pragma unroll 8
    for (int k = 0; k < 32; k++) {
      const float2 av = *(const float2*)&spb[k * 36 + ty * 2];
      const float2 bv = *(const float2*)&sqb[k * 36 + tx * 2];
      c00 = fmaf(av.x, bv.x, c00); c01 = fmaf(av.x, bv.y, c01);
      c10 = fmaf(av.y, bv.x, c10); c11 = fmaf(av.y, bv.y, c11);
    }
  }

  const int p0 = pb + ty * 2, q0 = qb + tx * 2;
  *(float2*)&C[p0 * 512 + q0]       = make_float2(c00, c01);
  *(float2*)&C[(p0 + 1) * 512 + q0] = make_float2(c10, c11);
  if (pb != qb) {  // mirror tile (C symmetric); diagonal tile already full
    *(float2*)&C[q0 * 512 + p0]       = make_float2(c00, c10);
    *(float2*)&C[(q0 + 1) * 512 + p0] = make_float2(c01, c11);
  }
}

extern "C" void kernel_launch(void* const* d_in, const int* in_sizes, int n_in,
                              void* d_out, int out_size, void* d_ws, size_t ws_size,
                              hipStream_t stream) {
  const float* x  = (const float*)d_in[0];
  const float* W1 = (const float*)d_in[1];
  const float* b1 = (const float*)d_in[2];
  const float* W2 = (const float*)d_in[3];
  const float* b2 = (const float*)d_in[4];
  const float* W3 = (const float*)d_in[5];
  const float* b3 = (const float*)d_in[6];
  float* out = (float*)d_out;
  char* ws = (char*)d_ws;

  float* Kp0 = (float*)ws;                          // 1 MB partial K (n 0..63)
  float* Kp1 = (float*)(ws + (1 << 20));            // 1 MB partial K (n 64..127)

  k_fused<<<256, 512, 0, stream>>>(x, W1, b1, b2, W3, b3, W2, Kp0, Kp1);
  k_atta2<<<136, 256, 0, stream>>>(Kp0, Kp1, out);
}